// Round 13
// baseline (314.929 us; speedup 1.0000x reference)
//
#include <hip/hip_runtime.h>
#include <math.h>

#define BB 2
#define TT 1024
#define DD 1536
#define HH 12
#define TQK 768
#define TVv 1536
#define CQKV 3072
#define NQKVG 4608   // qkv (3072) + g (1536) fused projection width
#define EPSF 1e-6f
#define TSC 32       // scan time-tile (per LDS buffer)

typedef __attribute__((ext_vector_type(8))) _Float16 half8v;
typedef __attribute__((ext_vector_type(4))) float f32x4;

__device__ __forceinline__ float siluf(float x) { return x / (1.f + expf(-x)); }

__device__ __forceinline__ uint pk2h(float a, float b) {
  union { _Float16 h[2]; uint u; } p;
  p.h[0] = (_Float16)a; p.h[1] = (_Float16)b;
  return p.u;
}

// async global->LDS. dest = wave-uniform base + lane*size; src is PER-LANE.
__device__ __forceinline__ void gload16(const void* g, void* l) {
  __builtin_amdgcn_global_load_lds(
      (const __attribute__((address_space(1))) void*)g,
      (__attribute__((address_space(3))) void*)l, 16, 0, 0);
}
__device__ __forceinline__ void gload4(const void* g, void* l) {
  __builtin_amdgcn_global_load_lds(
      (const __attribute__((address_space(1))) void*)g,
      (__attribute__((address_space(3))) void*)l, 4, 0, 0);
}

// DPP add: x += lane-permuted x. Pure VALU (no DS pipe).
template <int CTRL>
__device__ __forceinline__ float dpp_xadd(float x) {
  union { float f; int i; } a, b;
  a.f = x;
  b.i = __builtin_amdgcn_update_dpp(0, a.i, CTRL, 0xF, 0xF, true);
  return x + b.f;
}
__device__ __forceinline__ float red16_dpp(float x) {
  x = dpp_xadd<0xB1>(x);   // xor1
  x = dpp_xadd<0x4E>(x);   // xor2
  x = dpp_xadd<0x141>(x);  // row_half_mirror
  x = dpp_xadd<0x140>(x);  // row_mirror
  return x;
}

// ---------------------------------------------------------------------------
// fp16 MFMA GEMM: C = X(MxK,f16) @ W(NxK,f16)^T -> f32.
// 128x128 tile, BK=64, 4 waves (2x2), 4x4 frags of mfma_f32_16x16x32_f16.
// global_load_lds staging, XOR-swizzled source + swizzled ds_read.
// Output split: block-col c0 < nsplit -> C1 (ldc1), else C2 (ldc2).
// ---------------------------------------------------------------------------
__global__ __launch_bounds__(256) void gemm_f16(
    const ushort* __restrict__ X, const ushort* __restrict__ W,
    float* __restrict__ C1, float* __restrict__ C2,
    int M, int N, int K, int ldc1, int ldc2, int nsplit)
{
  __shared__ ushort Ah[128 * 64];
  __shared__ ushort Bh[128 * 64];
  const int tid  = threadIdx.x;
  const int lane = tid & 63;
  const int w    = tid >> 6;
  const int wr   = w >> 1, wc = w & 1;
  const int r0   = blockIdx.y * 128, c0 = blockIdx.x * 128;

  const int dr   = lane >> 3;
  const int slot = (lane & 7) ^ dr;

  f32x4 acc[4][4];
#pragma unroll
  for (int m = 0; m < 4; ++m)
#pragma unroll
    for (int n = 0; n < 4; ++n)
#pragma unroll
      for (int j = 0; j < 4; ++j) acc[m][n][j] = 0.f;

  for (int k0 = 0; k0 < K; k0 += 64) {
#pragma unroll
    for (int j = 0; j < 4; ++j) {
      const int row  = (w * 4 + j) * 8 + dr;
      const size_t xo = (size_t)(r0 + row) * K + k0 + slot * 8;
      const size_t wo = (size_t)(c0 + row) * K + k0 + slot * 8;
      const int ldso = (w * 4 + j) * 512;
      gload16(X + xo, Ah + ldso);
      gload16(W + wo, Bh + ldso);
    }
    __syncthreads();
#pragma unroll
    for (int kk = 0; kk < 2; ++kk) {
      const int kc8 = kk * 4 + (lane >> 4);
      const int sw  = (kc8 ^ (lane & 7)) << 3;
      half8v a[4], b[4];
#pragma unroll
      for (int m = 0; m < 4; ++m)
        a[m] = *(const half8v*)(Ah + (wr * 64 + m * 16 + (lane & 15)) * 64 + sw);
#pragma unroll
      for (int n = 0; n < 4; ++n)
        b[n] = *(const half8v*)(Bh + (wc * 64 + n * 16 + (lane & 15)) * 64 + sw);
#pragma unroll
      for (int m = 0; m < 4; ++m)
#pragma unroll
        for (int n = 0; n < 4; ++n)
          acc[m][n] = __builtin_amdgcn_mfma_f32_16x16x32_f16(a[m], b[n], acc[m][n], 0, 0, 0);
    }
    __syncthreads();
  }

  float* Cp; int ldc, cc0;
  if (c0 < nsplit) { Cp = C1; ldc = ldc1; cc0 = c0; }
  else             { Cp = C2; ldc = ldc2; cc0 = c0 - nsplit; }

  const int crow = (lane >> 4) * 4;
  const int ccol = lane & 15;
#pragma unroll
  for (int m = 0; m < 4; ++m)
#pragma unroll
    for (int j = 0; j < 4; ++j) {
      float* cp = Cp + (size_t)(r0 + wr * 64 + m * 16 + crow + j) * ldc + cc0 + wc * 64 + ccol;
#pragma unroll
      for (int n = 0; n < 4; ++n) cp[n * 16] = acc[m][n][j];
    }
}

// ---------------------------------------------------------------------------
// f32 -> fp16 casts (8 elems/thread, exact grids).
// ---------------------------------------------------------------------------
__device__ __forceinline__ void cast8_store(const float* f, ushort* dst, size_t e)
{
  uint4 pk;
  pk.x = pk2h(f[0], f[1]); pk.y = pk2h(f[2], f[3]);
  pk.z = pk2h(f[4], f[5]); pk.w = pk2h(f[6], f[7]);
  *(uint4*)(dst + e) = pk;
}

__global__ void cast_f16_kernel(const float* __restrict__ src, ushort* __restrict__ dst)
{
  int cid = blockIdx.x * blockDim.x + threadIdx.x;
  size_t e = (size_t)cid * 8;
  float f[8];
  *(float4*)(f)     = *(const float4*)(src + e);
  *(float4*)(f + 4) = *(const float4*)(src + e + 4);
  cast8_store(f, dst, e);
}

// Concatenated q|k|v|g weight cast into (4608,1536) fp16.
__global__ void cast_w4_kernel(const float* __restrict__ wq, const float* __restrict__ wk,
                               const float* __restrict__ wv, const float* __restrict__ wg,
                               ushort* __restrict__ dst)
{
  int cid = blockIdx.x * blockDim.x + threadIdx.x;
  size_t e = (size_t)cid * 8;
  const float* src; size_t off;
  if (e < 1179648)      { src = wq; off = e; }
  else if (e < 2359296) { src = wk; off = e - 1179648; }
  else if (e < 4718592) { src = wv; off = e - 2359296; }
  else                  { src = wg; off = e - 4718592; }
  float f[8];
  *(float4*)(f)     = *(const float4*)(src + off);
  *(float4*)(f + 4) = *(const float4*)(src + off + 4);
  cast8_store(f, dst, e);
}

// ---------------------------------------------------------------------------
// Causal depthwise conv (K=4) + SiLU + fused L2-norm (q,k heads).
// Wave = one 64-aligned c-chunk of one (b,t) row. Writes (B,H,T,D).
// ---------------------------------------------------------------------------
__global__ void conv_silu_kernel(
    const float* __restrict__ pre,
    const float* __restrict__ qw, const float* __restrict__ kw, const float* __restrict__ vw,
    float* __restrict__ qc, float* __restrict__ kc, float* __restrict__ vc)
{
  int idx = blockIdx.x * blockDim.x + threadIdx.x;
  int c  = idx % CQKV;
  int bt = idx / CQKV;
  int t  = bt % TT;
  int b  = bt / TT;

  const float* wp;
  if (c < TQK)          wp = qw + (size_t)c * 4;
  else if (c < 2 * TQK) wp = kw + (size_t)(c - TQK) * 4;
  else                  wp = vw + (size_t)(c - 2 * TQK) * 4;

  float s = 0.f;
#pragma unroll
  for (int j = 0; j < 4; ++j) {
    int ts = t - 3 + j;
    if (ts >= 0) s = fmaf(pre[(size_t)(b * TT + ts) * CQKV + c], wp[j], s);
  }
  s = siluf(s);

  if (c < 2 * TQK) {           // q or k: fused L2 norm over the 64-lane head
    float ss = s * s;
#pragma unroll
    for (int m = 32; m >= 1; m >>= 1) ss += __shfl_xor(ss, m, 64);
    s = s / fmaxf(sqrtf(ss), EPSF);
  }

  if (c < TQK) {
    int h = c >> 6, d = c & 63;
    qc[((size_t)(b * HH + h) * TT + t) * 64 + d] = s;
  } else if (c < 2 * TQK) {
    int c2 = c - TQK; int h = c2 >> 6, d = c2 & 63;
    kc[((size_t)(b * HH + h) * TT + t) * 64 + d] = s;
  } else {
    int c2 = c - 2 * TQK; int h = c2 >> 7, d = c2 & 127;
    vc[((size_t)(b * HH + h) * TT + t) * 128 + d] = s;
  }
}

// ---------------------------------------------------------------------------
// Gating: one block per row m; 4 waves x 6 outputs. Writes INTERLEAVED
// (alpha,beta) pairs: abi[((b*HH+h)*TT + t)*2 + {0,1}].
// ---------------------------------------------------------------------------
__global__ __launch_bounds__(256) void gate_kernel(
    const float* __restrict__ x, const float* __restrict__ w_a, const float* __restrict__ w_b,
    const float* __restrict__ A_log, const float* __restrict__ dt_bias,
    float* __restrict__ abi)
{
  const int m    = blockIdx.x;
  const int w    = threadIdx.x >> 6;
  const int lane = threadIdx.x & 63;
  const float* xr = x + (size_t)m * DD;
  float xv[24];
#pragma unroll
  for (int i = 0; i < 24; ++i) xv[i] = xr[lane + i * 64];
  const int b = m / TT, t = m % TT;
#pragma unroll
  for (int j = 0; j < 6; ++j) {
    int o = w * 6 + j;
    bool isA = o < HH;
    int h = isA ? o : o - HH;
    const float* wr = (isA ? w_a : w_b) + (size_t)h * DD;
    float s = 0.f;
#pragma unroll
    for (int i = 0; i < 24; ++i) s = fmaf(xv[i], wr[lane + i * 64], s);
#pragma unroll
    for (int mm = 32; mm >= 1; mm >>= 1) s += __shfl_xor(s, mm, 64);
    if (lane == 0) {
      size_t idx = ((size_t)(b * HH + h) * TT + t) * 2;
      if (isA) {
        float a  = s + dt_bias[h];
        float sp = (a > 20.f) ? a : log1pf(expf(a));
        abi[idx] = expf(-expf(A_log[h]) * sp);
      } else {
        abi[idx + 1] = 2.f / (1.f + expf(-s));
      }
    }
  }
}

// ---------------------------------------------------------------------------
// Gated delta scan v9: TWO v-column streams per wave (ILP fills the serial
// chain's stall -- R12 showed the scan is stall-bound, not issue-bound:
// removing 26% of insts changed VALUBusy 40->29% but not duration).
// Streams share k/q/alpha/beta (same head); colA = vg*8+cp, colB = colA+4.
// Per-step stores replaced by lane-s capture (all 16 lanes hold the reduced
// qs; lane s==i keeps step i's) -> 4 stores/tile, vmcnt stays encodable
// (steady-state wait = 4 stores + 21 loads = vmcnt(25)).
// 384 blocks = 16 vgroups x 24 bh, one wave each; blk = vg*24 + bh keeps
// same-bh blocks on XCD bh%8 (L2 dedupe of broadcast k/q).
// ---------------------------------------------------------------------------
__global__ __launch_bounds__(64) void scan_kernel(
    const float* __restrict__ qc, const float* __restrict__ kc, const float* __restrict__ vc,
    const float* __restrict__ abi, float* __restrict__ o)
{
  __shared__ float k0[TSC * 64], q0[TSC * 64], v0[TSC * 8], ab0[TSC * 2];
  __shared__ float k1[TSC * 64], q1[TSC * 64], v1[TSC * 8], ab1[TSC * 2];

  const int blk  = blockIdx.x;
  const int bh   = blk % 24;          // XCD affinity: bh%8
  const int vg   = blk / 24;          // 0..15
  const int b    = bh / HH, h = bh % HH;
  const int lane = threadIdx.x;       // 0..63
  const int cp   = lane >> 4;         // 0..3
  const int s    = lane & 15;         // 0..15, owns d = s*4..s*4+3

  const float* kg = kc + (size_t)bh * TT * 64;
  const float* qg = qc + (size_t)bh * TT * 64;

  // v gather: per gload4 j, lane covers (t_local = j*8 + (lane>>3),
  // c' = lane&7) with actual col = vg*8 + (c'&1)*4 + (c'>>1); LDS layout
  // VL[t_local*8 + c'] so compute reads a float2 at [i*8 + cp*2].
  const float* vsrc = vc + (size_t)bh * TT * 128 + (size_t)(lane >> 3) * 128
                      + vg * 8 + (lane & 1) * 4 + ((lane & 7) >> 1);
  const float* absrc = abi + (size_t)bh * TT * 2 + lane;

  // per-lane output bases: lane (cp,s) stores t = t0 + s (lo) / t0+16+s (hi)
  float* opA = o + ((size_t)(b * TT) * HH + h) * 128 + vg * 8 + cp + (size_t)s * HH * 128;
  float* opB = opA + 4;

#define STAGE(KL, QL, VL, ABL, T0) do { \
    _Pragma("unroll") \
    for (int j = 0; j < 8; ++j) { \
      gload16(kg + (size_t)((T0) + 4 * j) * 64 + lane * 4, &KL[j * 256]); \
      gload16(qg + (size_t)((T0) + 4 * j) * 64 + lane * 4, &QL[j * 256]); \
    } \
    _Pragma("unroll") \
    for (int j = 0; j < 4; ++j) \
      gload4(vsrc + (size_t)((T0) + j * 8) * 128, &VL[j * 64]); \
    gload4(absrc + (T0) * 2, &ABL[0]); \
  } while (0)

  float SA[4], SB[4];
#pragma unroll
  for (int i = 0; i < 4; ++i) { SA[i] = 0.f; SB[i] = 0.f; }

#define COMPUTE(KL, QL, VL, ABL, T0) do { \
    float4 kk = *(const float4*)(&KL[s * 4]); \
    float4 qq = *(const float4*)(&QL[s * 4]); \
    float2 vv = *(const float2*)(&VL[cp * 2]); \
    float2 ab = *(const float2*)(&ABL[0]); \
    float oAlo = 0.f, oAhi = 0.f, oBlo = 0.f, oBhi = 0.f; \
    _Pragma("unroll") \
    for (int i = 0; i < TSC; ++i) { \
      float4 kkn = kk, qqn = qq; float2 vvn = vv; float2 abn = ab; \
      if (i + 1 < TSC) { \
        kkn = *(const float4*)(&KL[(i + 1) * 64 + s * 4]); \
        qqn = *(const float4*)(&QL[(i + 1) * 64 + s * 4]); \
        vvn = *(const float2*)(&VL[(i + 1) * 8 + cp * 2]); \
        abn = *(const float2*)(&ABL[2 * (i + 1)]); \
      } \
      const float al = ab.x, albe = ab.x * ab.y; \
      float paA = fmaf(kk.y, SA[1], kk.x * SA[0]); \
      float pbA = fmaf(kk.w, SA[3], kk.z * SA[2]); \
      float paB = fmaf(kk.y, SB[1], kk.x * SB[0]); \
      float pbB = fmaf(kk.w, SB[3], kk.z * SB[2]); \
      float partA = red16_dpp(paA + pbA); \
      float partB = red16_dpp(paB + pbB); \
      const float cA = fmaf(-albe, partA, vv.x); \
      const float cB = fmaf(-albe, partB, vv.y); \
      SA[0] = fmaf(al, SA[0], cA * kk.x); SB[0] = fmaf(al, SB[0], cB * kk.x); \
      SA[1] = fmaf(al, SA[1], cA * kk.y); SB[1] = fmaf(al, SB[1], cB * kk.y); \
      SA[2] = fmaf(al, SA[2], cA * kk.z); SB[2] = fmaf(al, SB[2], cB * kk.z); \
      SA[3] = fmaf(al, SA[3], cA * kk.w); SB[3] = fmaf(al, SB[3], cB * kk.w); \
      float saA = fmaf(qq.y, SA[1], qq.x * SA[0]); \
      float sbA = fmaf(qq.w, SA[3], qq.z * SA[2]); \
      float saB = fmaf(qq.y, SB[1], qq.x * SB[0]); \
      float sbB = fmaf(qq.w, SB[3], qq.z * SB[2]); \
      float qsA = red16_dpp(saA + sbA); \
      float qsB = red16_dpp(saB + sbB); \
      if (i < 16) { \
        oAlo = (s == i) ? qsA : oAlo; \
        oBlo = (s == i) ? qsB : oBlo; \
      } else { \
        oAhi = (s == i - 16) ? qsA : oAhi; \
        oBhi = (s == i - 16) ? qsB : oBhi; \
      } \
      kk = kkn; qq = qqn; vv = vvn; ab = abn; \
    } \
    *(opA + (size_t)(T0) * HH * 128)      = oAlo; \
    *(opA + (size_t)((T0) + 16) * HH * 128) = oAhi; \
    *(opB + (size_t)(T0) * HH * 128)      = oBlo; \
    *(opB + (size_t)((T0) + 16) * HH * 128) = oBhi; \
  } while (0)

  // peel: fill both buffers, compute tile 0
  STAGE(k0, q0, v0, ab0, 0);
  STAGE(k1, q1, v1, ab1, TSC);
  asm volatile("s_waitcnt vmcnt(21)" ::: "memory");   // buf0 ready (21 newer = buf1)
  __builtin_amdgcn_sched_barrier(0);
  COMPUTE(k0, q0, v0, ab0, 0);                        // +4 stores

  for (int t0 = 2 * TSC; t0 < TT; t0 += 2 * TSC) {    // t0 = 64,128,...,960
    STAGE(k0, q0, v0, ab0, t0);                       // +21
    asm volatile("s_waitcnt vmcnt(25)" ::: "memory"); // buf1 ready (4 st + 21 loads newer)
    __builtin_amdgcn_sched_barrier(0);
    COMPUTE(k1, q1, v1, ab1, t0 - TSC);               // +4 stores
    STAGE(k1, q1, v1, ab1, t0 + TSC);                 // +21
    asm volatile("s_waitcnt vmcnt(25)" ::: "memory"); // buf0 ready
    __builtin_amdgcn_sched_barrier(0);
    COMPUTE(k0, q0, v0, ab0, t0);                     // +4 stores
  }
  asm volatile("s_waitcnt vmcnt(4)" ::: "memory");    // tail: buf1 holds tile 992
  __builtin_amdgcn_sched_barrier(0);
  COMPUTE(k1, q1, v1, ab1, TT - TSC);
#undef STAGE
#undef COMPUTE
}

// ---------------------------------------------------------------------------
// RMS norm over 128 + SiLU gate; emits fp16 for the final GEMM.
// ---------------------------------------------------------------------------
__global__ void rmsgate_kernel(const float* __restrict__ o, const float* __restrict__ gpre,
                               ushort* __restrict__ gof)
{
  int gid  = blockIdx.x * blockDim.x + threadIdx.x;
  int wid  = gid >> 6;
  int lane = threadIdx.x & 63;
  if (wid >= BB * TT * HH) return;
  int h = wid % HH;
  int m = wid / HH;
  const float* orow = o + (size_t)wid * 128;
  float2 ov = *(const float2*)(orow + lane * 2);
  float ss = ov.x * ov.x + ov.y * ov.y;
#pragma unroll
  for (int mm = 32; mm >= 1; mm >>= 1) ss += __shfl_xor(ss, mm, 64);
  float scale = rsqrtf(ss * (1.f / 128.f) + EPSF);
  const float* gr = gpre + (size_t)m * TVv + h * 128 + lane * 2;
  float o0 = ov.x * scale * siluf(gr[0]);
  float o1 = ov.y * scale * siluf(gr[1]);
  *(uint*)(gof + (size_t)m * TVv + h * 128 + lane * 2) = pk2h(o0, o1);
}

// ---------------------------------------------------------------------------
extern "C" void kernel_launch(void* const* d_in, const int* in_sizes, int n_in,
                              void* d_out, int out_size, void* d_ws, size_t ws_size,
                              hipStream_t stream) {
  (void)in_sizes; (void)n_in; (void)out_size; (void)ws_size;
  const float* x       = (const float*)d_in[0];
  const float* w_q     = (const float*)d_in[1];
  const float* w_k     = (const float*)d_in[2];
  const float* w_v     = (const float*)d_in[3];
  const float* w_a     = (const float*)d_in[4];
  const float* w_b     = (const float*)d_in[5];
  const float* w_g     = (const float*)d_in[6];
  const float* w_out   = (const float*)d_in[7];
  const float* A_log   = (const float*)d_in[8];
  const float* dt_bias = (const float*)d_in[9];
  const float* qcw     = (const float*)d_in[10];
  const float* kcw     = (const float*)d_in[11];
  const float* vcw     = (const float*)d_in[12];

  // Workspace (63.11 MB, same proven footprint).
  float* ws      = (float*)d_ws;
  float* qkv_pre = ws;
  float* g_pre   = ws + 6291456;
  float* Cu      = ws + 9437184;
  float* abi     = ws + 15728640;   // 49152 floats = 24576 (alpha,beta) pairs

  ushort* xf    = (ushort*)Cu;                 // 3,145,728 ushorts
  ushort* wcat  = (ushort*)(Cu + 1572864);     // 7,077,888 ushorts (q|k|v|g)

  float* qc = Cu;
  float* kc = Cu + 1572864;
  float* vc = Cu + 3145728;

  ushort* woutf = (ushort*)Cu;                 // 2,359,296 ushorts (phase 3)

  float*  o   = qkv_pre;
  ushort* gof = (ushort*)(qkv_pre + 3145728);  // 3,145,728 ushorts

  const int M = BB * TT;  // 2048
  dim3 blk(256);

  // 1) fp16 casts: x, concatenated q|k|v|g weights
  cast_f16_kernel<<<1536, blk, 0, stream>>>(x, xf);
  cast_w4_kernel<<<3456, blk, 0, stream>>>(w_q, w_k, w_v, w_g, wcat);

  // 2) fused qkv+g projection (N=4608, split epilogue)
  gemm_f16<<<dim3(NQKVG / 128, M / 128), blk, 0, stream>>>(
      xf, wcat, qkv_pre, g_pre, M, NQKVG, DD, CQKV, TVv, CQKV);

  // 3) gating coefficients -> interleaved (alpha,beta)
  gate_kernel<<<M, blk, 0, stream>>>(x, w_a, w_b, A_log, dt_bias, abi);

  // 4) causal depthwise conv + SiLU + fused L2 norm
  conv_silu_kernel<<<24576, blk, 0, stream>>>(qkv_pre, qcw, kcw, vcw, qc, kc, vc);

  // 5) scan v9: 2-stream ILP, 384 one-wave blocks
  scan_kernel<<<384, dim3(64), 0, stream>>>(qc, kc, vc, abi, o);

  // 6) cast w_out -> fp16 (into freed qc space)
  cast_f16_kernel<<<1152, blk, 0, stream>>>(w_out, woutf);

  // 7) RMS norm + SiLU gate -> fp16
  rmsgate_kernel<<<6144, blk, 0, stream>>>(o, g_pre, gof);

  // 8) output projection
  gemm_f16<<<dim3(TVv / 128, M / 128), blk, 0, stream>>>(
      gof, woutf, (float*)d_out, (float*)d_out, M, TVv, DD, TVv, TVv, TVv);
}